// Round 1
// baseline (125.607 us; speedup 1.0000x reference)
//
#include <hip/hip_runtime.h>

#define NN 50000
#define NE 320000
#define HID 256

// ---------------- flag kernels ----------------

__global__ void zero_flags_k(int* __restrict__ flags) {
    int i = blockIdx.x * blockDim.x + threadIdx.x;
    if (i < NN) flags[i] = 0;
}

// Detect int64 vs int32 edge_index layout. Values are in [0, 50000), so if the
// data is int64, EVERY odd 32-bit word (high dword) is 0. If int32, odd words
// are random values in [0,50000) — the chance the first 1024 are all zero is nil.
__global__ void detect_mode_k(const unsigned int* __restrict__ ei, int* __restrict__ mode) {
    __shared__ int any_nz;
    if (threadIdx.x == 0) any_nz = 0;
    __syncthreads();
    for (int i = threadIdx.x; i < 1024; i += blockDim.x) {
        if (ei[2 * i + 1] != 0u) any_nz = 1;   // benign race
    }
    __syncthreads();
    if (threadIdx.x == 0) mode[0] = (any_nz == 0) ? 1 : 0;   // 1 => int64
}

__global__ void set_flags_k(const int* __restrict__ ei32, int* __restrict__ flags,
                            const int* __restrict__ mode) {
    int e = blockIdx.x * blockDim.x + threadIdx.x;
    if (e >= NE) return;
    int t;
    if (mode[0]) t = ei32[2 * (NE + e)];   // low dword of int64 element [1][e]
    else         t = ei32[NE + e];         // int32 element [1][e]
    if (t >= 0 && t < NN) flags[t] = 1;    // benign race, deterministic
}

// ---------------- W2 = Wv @ Wo  (256x256x256) ----------------

__global__ void w2_k(const float* __restrict__ Wv, const float* __restrict__ Wo,
                     float* __restrict__ W2) {
    int i = blockIdx.x;    // row
    int j = threadIdx.x;   // col
    float acc = 0.f;
    #pragma unroll 8
    for (int k = 0; k < HID; ++k)
        acc = fmaf(Wv[i * HID + k], Wo[k * HID + j], acc);
    W2[i * HID + j] = acc;
}

// ---------------- out = mask ? x @ W2 + bo : bo ----------------

#define BM 64
#define BN 64
#define BK 16

__global__ __launch_bounds__(256) void out_gemm_k(
    const float* __restrict__ x, const float* __restrict__ W2,
    const float* __restrict__ bo, const int* __restrict__ flags,
    float* __restrict__ out)
{
    __shared__ float As[BK][BM];   // A tile stored transposed: As[k][row]
    __shared__ float Bs[BK][BN];

    const int row0 = blockIdx.x * BM;
    const int col0 = blockIdx.y * BN;
    const int tx = threadIdx.x;    // 0..15
    const int ty = threadIdx.y;    // 0..15
    const int tid = ty * 16 + tx;

    // A-load mapping: each thread loads one float4 of the 64x16 x-tile
    const int ar = tid >> 2;            // row within tile, 0..63
    const int ak = (tid & 3) << 2;      // k offset, 0/4/8/12
    int arow = row0 + ar;
    if (arow >= NN) arow = NN - 1;      // clamp (tail block), duplicate loads harmless

    // B-load mapping: each thread loads one float4 of the 16x64 W2-tile
    const int br = tid >> 4;            // k within tile, 0..15
    const int bc = (tid & 15) << 2;     // col offset, 0..60

    float acc[4][4] = {};

    for (int k0 = 0; k0 < HID; k0 += BK) {
        const float4 av = *reinterpret_cast<const float4*>(&x[arow * HID + k0 + ak]);
        const float4 bv = *reinterpret_cast<const float4*>(&W2[(k0 + br) * HID + col0 + bc]);

        As[ak + 0][ar] = av.x;
        As[ak + 1][ar] = av.y;
        As[ak + 2][ar] = av.z;
        As[ak + 3][ar] = av.w;
        *reinterpret_cast<float4*>(&Bs[br][bc]) = bv;
        __syncthreads();

        #pragma unroll
        for (int k = 0; k < BK; ++k) {
            const float4 a4 = *reinterpret_cast<const float4*>(&As[k][ty * 4]);
            const float4 b4 = *reinterpret_cast<const float4*>(&Bs[k][tx * 4]);
            const float a[4] = {a4.x, a4.y, a4.z, a4.w};
            const float b[4] = {b4.x, b4.y, b4.z, b4.w};
            #pragma unroll
            for (int m = 0; m < 4; ++m)
                #pragma unroll
                for (int n = 0; n < 4; ++n)
                    acc[m][n] = fmaf(a[m], b[n], acc[m][n]);
        }
        __syncthreads();
    }

    #pragma unroll
    for (int m = 0; m < 4; ++m) {
        const int r = row0 + ty * 4 + m;
        if (r >= NN) continue;
        const float msk = flags[r] ? 1.f : 0.f;
        #pragma unroll
        for (int n = 0; n < 4; ++n) {
            const int c = col0 + tx * 4 + n;
            out[r * HID + c] = fmaf(msk, acc[m][n], bo[c]);
        }
    }
}

// ---------------- launch ----------------

extern "C" void kernel_launch(void* const* d_in, const int* in_sizes, int n_in,
                              void* d_out, int out_size, void* d_ws, size_t ws_size,
                              hipStream_t stream) {
    const float* x   = (const float*)d_in[0];
    const int*   ei  = (const int*)d_in[1];
    // d_in[2] = edge_attr (unused), d_in[3] = Wq (unused), d_in[4] = Wk (unused)
    const float* Wv  = (const float*)d_in[5];
    // d_in[6] = We (unused)
    const float* Wo  = (const float*)d_in[7];
    const float* bo  = (const float*)d_in[8];
    float* out = (float*)d_out;

    // workspace layout
    char* ws = (char*)d_ws;
    float* W2   = (float*)ws;                       // 256*256*4 = 256 KiB
    int*   flags = (int*)(ws + HID * HID * 4);      // 50000*4
    int*   mode  = flags + NN;                      // 4 bytes

    zero_flags_k<<<(NN + 255) / 256, 256, 0, stream>>>(flags);
    detect_mode_k<<<1, 256, 0, stream>>>((const unsigned int*)ei, mode);
    set_flags_k<<<(NE + 255) / 256, 256, 0, stream>>>(ei, flags, mode);
    w2_k<<<HID, HID, 0, stream>>>(Wv, Wo, W2);

    dim3 block(16, 16);
    dim3 grid((NN + BM - 1) / BM, HID / BN);
    out_gemm_k<<<grid, block, 0, stream>>>(x, W2, bo, flags, out);
}

// Round 2
// 52.098 us; speedup vs baseline: 2.4110x; 2.4110x over previous
//
#include <hip/hip_runtime.h>

#define NN 50000
#define NE 320000
#define HID 256
#define NBLK_FLAG 1250            // ceil(NE/256)

typedef __attribute__((ext_vector_type(8))) short bf16x8;   // 8 bf16 = 4 VGPR
typedef __attribute__((ext_vector_type(4))) float f32x4;

static __device__ __forceinline__ unsigned short f2bf(float f) {
    union { float f; unsigned u; } c; c.f = f;
    unsigned u = c.u;
    return (unsigned short)((u + 0x7fffu + ((u >> 16) & 1u)) >> 16);  // RNE
}

// ---------------- prep: flags scatter + W2=Wv@Wo (bf16, swizzled B image) ----------------
//
// wsB image layout (what the GEMM wants as its LDS picture, per 64-k tile):
//   tile kt (0..3), 32 KiB each: for col j (0..255), 128 B row of k'=0..63 bf16,
//   16B slot s = k'>>3 stored at slot (s ^ (j&7))  [XOR swizzle]
__global__ void prep_k(const int* __restrict__ ei, int* __restrict__ flags,
                       const float* __restrict__ Wv, const float* __restrict__ Wo,
                       unsigned short* __restrict__ wsB) {
    const int b = blockIdx.x;
    if (b < NBLK_FLAG) {
        // detect int64 vs int32: if int64, high dwords are all zero
        __shared__ int nz;
        if (threadIdx.x == 0) nz = 0;
        __syncthreads();
        unsigned hv = ((const unsigned*)ei)[2 * threadIdx.x + 1];
        if (hv != 0u) nz = 1;              // benign same-value race
        __syncthreads();
        const int is64 = (nz == 0);
        const int e = b * 256 + threadIdx.x;
        if (e < NE) {
            int t = is64 ? ei[2 * (NE + e)] : ei[NE + e];
            if (t >= 0 && t < NN) flags[t] = 1;   // benign same-value race
        }
    } else {
        const int i = b - NBLK_FLAG;       // W2 row == GEMM k index, 0..255
        const int j = threadIdx.x;         // W2 col, 0..255
        float acc = 0.f;
        #pragma unroll 8
        for (int k = 0; k < HID; ++k)
            acc = fmaf(Wv[i * HID + k], Wo[k * HID + j], acc);
        const int kt = i >> 6, kp = i & 63;
        const int byte = kt * 32768 + j * 128 + (((kp >> 3) ^ (j & 7)) << 4) + ((kp & 7) << 1);
        wsB[byte >> 1] = f2bf(acc);
    }
}

// ---------------- out = mask ? x @ W2 + bo : bo  (bf16 MFMA) ----------------
// block: 256 threads (4 waves). Tile 64 rows x 256 cols, BK=64, K=256.
// wave w owns cols [w*64, w*64+64): 4x4 fragments of 16x16x32.

__global__ __launch_bounds__(256) void out_gemm_k(
    const float* __restrict__ x, const unsigned short* __restrict__ wsB,
    const float* __restrict__ bo, const int* __restrict__ flags,
    float* __restrict__ out)
{
    __shared__ char lds[8192 + 32768];
    char* As = lds;                 // [64 rows][128 B]  (64 bf16 k, swizzled slots)
    char* Bs = lds + 8192;          // [256 cols][128 B] (64 bf16 k, swizzled slots)

    const int tid  = threadIdx.x;
    const int wave = tid >> 6;
    const int lane = tid & 63;
    const int rl   = lane & 15;
    const int hi   = lane >> 4;
    const int row0 = blockIdx.x * 64;
    const int wcol = wave * 64;

    // A staging map: thread -> (row ar, k-quarter aq)
    const int ar = tid >> 2;          // 0..63
    const int aq = tid & 3;           // 0..3  (16 k-elements each)
    int grow = row0 + ar; if (grow >= NN) grow = NN - 1;   // clamp tail (dup loads harmless)
    const float* asrc = x + (size_t)grow * HID;

    f32x4 acc[4][4];
    #pragma unroll
    for (int m = 0; m < 4; ++m)
        #pragma unroll
        for (int n = 0; n < 4; ++n)
            acc[m][n] = (f32x4){0.f, 0.f, 0.f, 0.f};

    for (int kt = 0; kt < 4; ++kt) {
        // ---- stage A: 16 f32 -> 16 bf16, two swizzled b128 writes ----
        const float4* ap = (const float4*)(asrc + kt * 64 + aq * 16);
        float4 v0 = ap[0], v1 = ap[1], v2 = ap[2], v3 = ap[3];
        bf16x8 w0, w1;
        w0[0] = (short)f2bf(v0.x); w0[1] = (short)f2bf(v0.y);
        w0[2] = (short)f2bf(v0.z); w0[3] = (short)f2bf(v0.w);
        w0[4] = (short)f2bf(v1.x); w0[5] = (short)f2bf(v1.y);
        w0[6] = (short)f2bf(v1.z); w0[7] = (short)f2bf(v1.w);
        w1[0] = (short)f2bf(v2.x); w1[1] = (short)f2bf(v2.y);
        w1[2] = (short)f2bf(v2.z); w1[3] = (short)f2bf(v2.w);
        w1[4] = (short)f2bf(v3.x); w1[5] = (short)f2bf(v3.y);
        w1[6] = (short)f2bf(v3.z); w1[7] = (short)f2bf(v3.w);
        const int s0 = (aq * 2)     ^ (ar & 7);
        const int s1 = (aq * 2 + 1) ^ (ar & 7);
        *(bf16x8*)(As + ar * 128 + s0 * 16) = w0;
        *(bf16x8*)(As + ar * 128 + s1 * 16) = w1;

        // ---- stage B: 32 KiB pre-swizzled image -> LDS via global_load_lds x16B ----
        const char* gB = (const char*)wsB + kt * 32768;
        #pragma unroll
        for (int it = 0; it < 8; ++it) {
            const int off = (it * 4 + wave) * 1024;
            __builtin_amdgcn_global_load_lds(
                (const __attribute__((address_space(1))) unsigned int*)(gB + off + lane * 16),
                (__attribute__((address_space(3))) unsigned int*)(Bs + off),
                16, 0, 0);
        }
        __syncthreads();   // drains vmcnt+lgkmcnt before barrier (compiler-enforced)

        // ---- MFMA: 2 kk-steps x 4x4 fragments ----
        #pragma unroll
        for (int kk = 0; kk < 2; ++kk) {
            const int swz = (((kk << 2) + hi) ^ (rl & 7)) << 4;
            bf16x8 af[4], bf[4];
            #pragma unroll
            for (int m = 0; m < 4; ++m)
                af[m] = *(const bf16x8*)(As + (m * 16 + rl) * 128 + swz);
            #pragma unroll
            for (int n = 0; n < 4; ++n)
                bf[n] = *(const bf16x8*)(Bs + (wcol + n * 16 + rl) * 128 + swz);
            #pragma unroll
            for (int m = 0; m < 4; ++m)
                #pragma unroll
                for (int n = 0; n < 4; ++n)
                    acc[m][n] = __builtin_amdgcn_mfma_f32_16x16x32_bf16(af[m], bf[n], acc[m][n], 0, 0, 0);
        }
        __syncthreads();   // LDS reused next kt
    }

    // ---- epilogue: out[r] = flags[r] ? acc + bo : bo ----
    float bov[4];
    #pragma unroll
    for (int n = 0; n < 4; ++n) bov[n] = bo[wcol + n * 16 + rl];

    #pragma unroll
    for (int m = 0; m < 4; ++m) {
        #pragma unroll
        for (int j = 0; j < 4; ++j) {
            const int row = row0 + m * 16 + hi * 4 + j;   // C/D: col=lane&15, row=(lane>>4)*4+reg
            if (row < NN) {
                const float msk = flags[row] ? 1.f : 0.f;
                float* orow = out + (size_t)row * HID + wcol + rl;
                #pragma unroll
                for (int n = 0; n < 4; ++n)
                    orow[n * 16] = fmaf(msk, acc[m][n][j], bov[n]);
            }
        }
    }
}

// ---------------- launch ----------------

extern "C" void kernel_launch(void* const* d_in, const int* in_sizes, int n_in,
                              void* d_out, int out_size, void* d_ws, size_t ws_size,
                              hipStream_t stream) {
    const float* x   = (const float*)d_in[0];
    const int*   ei  = (const int*)d_in[1];
    const float* Wv  = (const float*)d_in[5];
    const float* Wo  = (const float*)d_in[7];
    const float* bo  = (const float*)d_in[8];
    float* out = (float*)d_out;

    // workspace: [0,128K) = swizzled bf16 W2 image; then flags
    unsigned short* wsB = (unsigned short*)d_ws;
    int* flags = (int*)((char*)d_ws + 4 * 32768);

    hipMemsetAsync(flags, 0, NN * sizeof(int), stream);
    prep_k<<<NBLK_FLAG + HID, 256, 0, stream>>>(ei, flags, Wv, Wo, wsB);

    dim3 grid((NN + 63) / 64);
    out_gemm_k<<<grid, 256, 0, stream>>>(x, wsB, bo, flags, out);
}

// Round 3
// 45.680 us; speedup vs baseline: 2.7497x; 1.1405x over previous
//
#include <hip/hip_runtime.h>

#define NN 50000
#define NE 320000
#define HID 256
#define NBLK_FLAG 1250            // ceil(NE/256)

typedef __attribute__((ext_vector_type(8))) short bf16x8;   // 8 bf16 = 4 VGPR
typedef __attribute__((ext_vector_type(4))) float f32x4;

static __device__ __forceinline__ unsigned short f2bf(float f) {
    union { float f; unsigned u; } c; c.f = f;
    unsigned u = c.u;
    return (unsigned short)((u + 0x7fffu + ((u >> 16) & 1u)) >> 16);  // RNE
}

// ---------------- prep: flags scatter + W2=Wv@Wo (bf16 fragment image) ----------------
//
// wsB image layout = exactly the per-wave MFMA B fragments, coalesced:
//   byte off = kt*32768 + c16*2048 + kk*1024 + h*256 + rl*16 + e*2
// where k = kt*64 + kk*32 + h*8 + e  (h = lane>>4, e = elem 0..7), col = c16*16 + rl.
// For fixed (kt,c16,kk) the 64 lanes of a wave read 64 consecutive 16B chunks (1 KiB).
__global__ void prep_k(const int* __restrict__ ei, int* __restrict__ flags,
                       const float* __restrict__ Wv, const float* __restrict__ Wo,
                       unsigned short* __restrict__ wsB) {
    const int b = blockIdx.x;
    if (b < NBLK_FLAG) {
        // detect int64 vs int32: if int64, high dwords are all zero
        __shared__ int nz;
        if (threadIdx.x == 0) nz = 0;
        __syncthreads();
        unsigned hv = ((const unsigned*)ei)[2 * threadIdx.x + 1];
        if (hv != 0u) nz = 1;              // benign same-value race
        __syncthreads();
        const int is64 = (nz == 0);
        const int e = b * 256 + threadIdx.x;
        if (e < NE) {
            int t = is64 ? ei[2 * (NE + e)] : ei[NE + e];
            if (t >= 0 && t < NN) flags[t] = 1;   // benign same-value race
        }
    } else {
        const int i = b - NBLK_FLAG;       // W2 row == GEMM k index, 0..255
        const int j = threadIdx.x;         // W2 col, 0..255
        const float* wv = Wv + i * HID;
        float a0 = 0.f, a1 = 0.f, a2 = 0.f, a3 = 0.f;
        #pragma unroll 4
        for (int k = 0; k < HID; k += 4) {
            a0 = fmaf(wv[k + 0], Wo[(k + 0) * HID + j], a0);
            a1 = fmaf(wv[k + 1], Wo[(k + 1) * HID + j], a1);
            a2 = fmaf(wv[k + 2], Wo[(k + 2) * HID + j], a2);
            a3 = fmaf(wv[k + 3], Wo[(k + 3) * HID + j], a3);
        }
        const float acc = (a0 + a1) + (a2 + a3);
        const int kt = i >> 6, kp = i & 63;
        const int kk = kp >> 5, h = (kp >> 3) & 3, e = kp & 7;
        const int byte = kt * 32768 + (j >> 4) * 2048 + kk * 1024 + h * 256 + (j & 15) * 16 + e * 2;
        wsB[byte >> 1] = f2bf(acc);
    }
}

// ---------------- out = mask ? x @ W2 + bo : bo  (bf16 MFMA) ----------------
// 256 threads (4 waves), tile 64 rows x 256 cols. Wave w owns cols [w*64,w*64+64).
// A: f32->bf16 staged in LDS, double-buffered (2x8KB), XOR-swizzled rows.
// B: direct global->reg fragment loads from the L2-resident wsB image (no LDS).

__global__ __launch_bounds__(256) void out_gemm_k(
    const float* __restrict__ x, const unsigned short* __restrict__ wsB,
    const float* __restrict__ bo, const int* __restrict__ flags,
    float* __restrict__ out)
{
    __shared__ char As[2][8192];    // [buf][64 rows][128 B] (64 bf16 k, swizzled 16B slots)

    const int tid  = threadIdx.x;
    const int wave = tid >> 6;
    const int lane = tid & 63;
    const int rl   = lane & 15;
    const int hi   = lane >> 4;
    const int row0 = blockIdx.x * 64;
    const int wcol = wave * 64;

    // A staging map: thread -> (row ar, k-quarter aq)
    const int ar = tid >> 2;          // 0..63
    const int aq = tid & 3;           // 0..3  (16 k-elements each)
    int grow = row0 + ar; if (grow >= NN) grow = NN - 1;   // clamp tail (dup loads harmless)
    const float* asrc = x + (size_t)grow * HID;
    const int s0 = ((aq * 2)     ^ (ar & 7)) << 4;
    const int s1 = ((aq * 2 + 1) ^ (ar & 7)) << 4;

    f32x4 acc[4][4];
    #pragma unroll
    for (int m = 0; m < 4; ++m)
        #pragma unroll
        for (int n = 0; n < 4; ++n)
            acc[m][n] = (f32x4){0.f, 0.f, 0.f, 0.f};

    // ---- prologue: stage A tile 0 into buf 0 ----
    {
        const float4* ap = (const float4*)(asrc + aq * 16);
        float4 v0 = ap[0], v1 = ap[1], v2 = ap[2], v3 = ap[3];
        bf16x8 w0, w1;
        w0[0] = (short)f2bf(v0.x); w0[1] = (short)f2bf(v0.y);
        w0[2] = (short)f2bf(v0.z); w0[3] = (short)f2bf(v0.w);
        w0[4] = (short)f2bf(v1.x); w0[5] = (short)f2bf(v1.y);
        w0[6] = (short)f2bf(v1.z); w0[7] = (short)f2bf(v1.w);
        w1[0] = (short)f2bf(v2.x); w1[1] = (short)f2bf(v2.y);
        w1[2] = (short)f2bf(v2.z); w1[3] = (short)f2bf(v2.w);
        w1[4] = (short)f2bf(v3.x); w1[5] = (short)f2bf(v3.y);
        w1[6] = (short)f2bf(v3.z); w1[7] = (short)f2bf(v3.w);
        *(bf16x8*)(As[0] + ar * 128 + s0) = w0;
        *(bf16x8*)(As[0] + ar * 128 + s1) = w1;
    }
    __syncthreads();

    const char* gB = (const char*)wsB;

    #pragma unroll
    for (int kt = 0; kt < 4; ++kt) {
        // ---- issue next A-tile global loads early (hide HBM latency under compute) ----
        float4 v0, v1, v2, v3;
        if (kt < 3) {
            const float4* ap = (const float4*)(asrc + (kt + 1) * 64 + aq * 16);
            v0 = ap[0]; v1 = ap[1]; v2 = ap[2]; v3 = ap[3];
        }

        // ---- B fragments: direct global->reg, coalesced 1KB per (n,kk) per wave ----
        bf16x8 bfrag[4][2];
        #pragma unroll
        for (int n = 0; n < 4; ++n)
            #pragma unroll
            for (int kk = 0; kk < 2; ++kk)
                bfrag[n][kk] = *(const bf16x8*)(gB + kt * 32768 + (wave * 4 + n) * 2048
                                                + kk * 1024 + lane * 16);

        // ---- MFMA on current buffer ----
        const char* Ac = As[kt & 1];
        #pragma unroll
        for (int kk = 0; kk < 2; ++kk) {
            const int swz = (((kk << 2) + hi) ^ (rl & 7)) << 4;
            bf16x8 af[4];
            #pragma unroll
            for (int m = 0; m < 4; ++m)
                af[m] = *(const bf16x8*)(Ac + (m * 16 + rl) * 128 + swz);
            #pragma unroll
            for (int m = 0; m < 4; ++m)
                #pragma unroll
                for (int n = 0; n < 4; ++n)
                    acc[m][n] = __builtin_amdgcn_mfma_f32_16x16x32_bf16(af[m], bfrag[n][kk], acc[m][n], 0, 0, 0);
        }

        // ---- convert + write next buffer ----
        if (kt < 3) {
            bf16x8 w0, w1;
            w0[0] = (short)f2bf(v0.x); w0[1] = (short)f2bf(v0.y);
            w0[2] = (short)f2bf(v0.z); w0[3] = (short)f2bf(v0.w);
            w0[4] = (short)f2bf(v1.x); w0[5] = (short)f2bf(v1.y);
            w0[6] = (short)f2bf(v1.z); w0[7] = (short)f2bf(v1.w);
            w1[0] = (short)f2bf(v2.x); w1[1] = (short)f2bf(v2.y);
            w1[2] = (short)f2bf(v2.z); w1[3] = (short)f2bf(v2.w);
            w1[4] = (short)f2bf(v3.x); w1[5] = (short)f2bf(v3.y);
            w1[6] = (short)f2bf(v3.z); w1[7] = (short)f2bf(v3.w);
            char* An = As[(kt + 1) & 1];
            *(bf16x8*)(An + ar * 128 + s0) = w0;
            *(bf16x8*)(An + ar * 128 + s1) = w1;
        }
        __syncthreads();
    }

    // ---- epilogue: out[r] = flags[r] ? acc + bo : bo ----
    float bov[4];
    #pragma unroll
    for (int n = 0; n < 4; ++n) bov[n] = bo[wcol + n * 16 + rl];

    #pragma unroll
    for (int m = 0; m < 4; ++m) {
        #pragma unroll
        for (int j = 0; j < 4; ++j) {
            const int row = row0 + m * 16 + hi * 4 + j;   // C/D: col=lane&15, row=(lane>>4)*4+reg
            if (row < NN) {
                const float msk = flags[row] ? 1.f : 0.f;
                float* orow = out + (size_t)row * HID + wcol + rl;
                #pragma unroll
                for (int n = 0; n < 4; ++n)
                    orow[n * 16] = fmaf(msk, acc[m][n][j], bov[n]);
            }
        }
    }
}

// ---------------- launch ----------------

extern "C" void kernel_launch(void* const* d_in, const int* in_sizes, int n_in,
                              void* d_out, int out_size, void* d_ws, size_t ws_size,
                              hipStream_t stream) {
    const float* x   = (const float*)d_in[0];
    const int*   ei  = (const int*)d_in[1];
    const float* Wv  = (const float*)d_in[5];
    const float* Wo  = (const float*)d_in[7];
    const float* bo  = (const float*)d_in[8];
    float* out = (float*)d_out;

    // workspace: [0,128K) = bf16 W2 fragment image; then flags
    unsigned short* wsB = (unsigned short*)d_ws;
    int* flags = (int*)((char*)d_ws + 4 * 32768);

    hipMemsetAsync(flags, 0, NN * sizeof(int), stream);
    prep_k<<<NBLK_FLAG + HID, 256, 0, stream>>>(ei, flags, Wv, Wo, wsB);

    dim3 grid((NN + 63) / 64);
    out_gemm_k<<<grid, 256, 0, stream>>>(x, wsB, bo, flags, out);
}